// Round 1
// baseline (355.620 us; speedup 1.0000x reference)
//
#include <hip/hip_runtime.h>

#define B_ 8
#define T_ 1024
#define CG_ 256

// ---------------- pack: x (8,1024,1024) f32 -> tok rows (B*Cg, T) u8 ----------------
__global__ __launch_bounds__(256) void pack_kernel(const float* __restrict__ x,
                                                   unsigned char* __restrict__ tok){
  __shared__ unsigned char tl[256][80];          // [g][tt], 80 keeps rows 16B-aligned
  const int b  = blockIdx.x >> 4;                // 8 b * 16 t-tiles = 128 blocks
  const int t0 = (blockIdx.x & 15) << 6;
  const int g  = threadIdx.x;                    // 0..255
  const float* xb = x + ((size_t)(b*T_ + t0) * 1024) + g*4;
  for (int tt = 0; tt < 64; tt++){
    const float4 v = *reinterpret_cast<const float4*>(xb + (size_t)tt*1024);
    unsigned int t = (v.x>0.f?1u:0u) | (v.y>0.f?2u:0u) | (v.z>0.f?4u:0u) | (v.w>0.f?8u:0u);
    tl[g][tt] = (unsigned char)t;
  }
  __syncthreads();
  const int gg  = threadIdx.x >> 2;
  const int off = (threadIdx.x & 3) * 16;
  for (int it = 0; it < 4; it++){
    const int g2 = gg + it*64;
    const uint4 w = *reinterpret_cast<const uint4*>(&tl[g2][off]);
    *reinterpret_cast<uint4*>(tok + (size_t)(b*CG_ + g2)*T_ + t0 + off) = w;
  }
}

// ---------------- ROSA DP: one wave per row ----------------
__device__ __forceinline__ unsigned int wave_allmax(unsigned int v){
  int x = (int)v, t;
  t = __builtin_amdgcn_update_dpp(x, x, 0x111, 0xf, 0xf, false); x = t > x ? t : x; // row_shr:1
  t = __builtin_amdgcn_update_dpp(x, x, 0x112, 0xf, 0xf, false); x = t > x ? t : x; // row_shr:2
  t = __builtin_amdgcn_update_dpp(x, x, 0x114, 0xf, 0xf, false); x = t > x ? t : x; // row_shr:4
  t = __builtin_amdgcn_update_dpp(x, x, 0x118, 0xf, 0xf, false); x = t > x ? t : x; // row_shr:8
  t = __builtin_amdgcn_update_dpp(x, x, 0x142, 0xf, 0xf, false); x = t > x ? t : x; // row_bcast:15
  t = __builtin_amdgcn_update_dpp(x, x, 0x143, 0xf, 0xf, false); x = t > x ? t : x; // row_bcast:31
  return (unsigned int)__builtin_amdgcn_readlane(x, 63);
}

__global__ __launch_bounds__(256, 2) void rosa_dp_kernel(const unsigned char* __restrict__ tok,
                                                         unsigned char* __restrict__ pred){
  __shared__ unsigned char tlds[4][1024];
  const int wave = threadIdx.x >> 6;
  const unsigned int lane = threadIdx.x & 63u;
  const int row = blockIdx.x * 4 + wave;
  unsigned char* mylds = &tlds[wave][0];
  {
    const uint4 v = *reinterpret_cast<const uint4*>(tok + (size_t)row*T_ + lane*16);
    *reinterpret_cast<uint4*>(mylds + lane*16) = v;
  }
  __syncthreads();

  unsigned int tokr[16], oldv[16], jv[16];
  #pragma unroll
  for (int k=0;k<16;k++){ tokr[k] = mylds[k*64 + lane]; oldv[k] = 0u; jv[k] = (unsigned int)(k*64) + lane; }
  const int perm = (int)(((lane + 63u) & 63u) << 2);  // ds_bpermute addr: pull from lane-1 (rot)
  const bool lane0 = (lane == 0u);

  #pragma unroll
  for (int i0 = 0; i0 < 16; i0++){
    unsigned int pr = 0u;
    unsigned int pend_tok = 0u, pend_valid = 0u; int pend_di = 64;
    #pragma unroll 1
    for (int di = 0; di < 64; di++){
      // broadcast token x[i], i = i0*64+di, from the lane that owns it (chunk i0, lane di)
      const unsigned int xi = (unsigned int)__builtin_amdgcn_readlane((int)tokr[i0], di);
      unsigned int best = 0u, carry = 0u;
      #pragma unroll
      for (int k = 0; k <= i0; k++){
        const unsigned int rot = (unsigned int)__builtin_amdgcn_ds_bpermute(perm, (int)oldv[k]);
        const unsigned int shifted = lane0 ? carry : rot;   // lane0 takes prev chunk's lane63
        carry = rot;                                        // lane0's rot == old[k][63]
        const unsigned int nv = (tokr[k] == xi) ? (shifted + 1u) : 0u;
        oldv[k] = nv;
        unsigned int key = (nv << 10) + jv[k];              // run<<10 | j ; run==0 -> key<1024
        if (k == i0) key = (lane < (unsigned int)di) ? key : 0u;  // only boundary chunk needs j<i mask
        best = key > best ? key : best;
      }
      // commit previous step's pred (its LDS read has had a full step of latency cover)
      { const unsigned int pp = pend_valid ? pend_tok : 0u;
        pr = ((int)lane == pend_di) ? pp : pr; }
      const unsigned int ab = wave_allmax(best);
      unsigned int pidx = (ab & 1023u) + 1u;
      pidx = pidx > 1023u ? 1023u : pidx;                   // min(best_j+1, T-1)
      pend_tok = (unsigned int)mylds[pidx];
      pend_valid = (ab >= 1024u) ? 1u : 0u;                 // max run == 0 -> no match -> 0
      pend_di = di;
    }
    { const unsigned int pp = pend_valid ? pend_tok : 0u;
      pr = ((int)lane == pend_di) ? pp : pr; }
    pred[(size_t)row*T_ + i0*64 + lane] = (unsigned char)pr;
  }
}

// ---------------- expand: pred (B*Cg, T) u8 -> out (B,T,C) f32 ----------------
__global__ __launch_bounds__(256) void expand_kernel(const unsigned char* __restrict__ pred,
                                                     const float* __restrict__ emb0,
                                                     const float* __restrict__ emb1,
                                                     float* __restrict__ out){
  __shared__ unsigned char pl[64][80];
  const int bid = blockIdx.x;                 // 8 b * 16 t-tiles * 4 g-tiles = 512
  const int g0 = (bid & 3) << 6;
  const int t0 = ((bid >> 2) & 15) << 6;
  const int b  = bid >> 6;
  const int k  = threadIdx.x;
  {
    const int gg = k >> 2, off = (k & 3) * 16;
    const uint4 v = *reinterpret_cast<const uint4*>(pred + (size_t)(b*CG_ + g0 + gg)*T_ + t0 + off);
    *reinterpret_cast<uint4*>(&pl[gg][off]) = v;
  }
  __syncthreads();
  const int gg = k & 63;
  const int w  = k >> 6;
  const float4 e0 = *reinterpret_cast<const float4*>(emb0 + (g0+gg)*4);
  const float4 e1 = *reinterpret_cast<const float4*>(emb1 + (g0+gg)*4);
  for (int it = 0; it < 16; it++){
    const int tt = it*4 + w;
    const unsigned int pb = pl[gg][tt];
    float4 o;
    o.x = (pb & 1u) ? e1.x : e0.x;
    o.y = (pb & 2u) ? e1.y : e0.y;
    o.z = (pb & 4u) ? e1.z : e0.z;
    o.w = (pb & 8u) ? e1.w : e0.w;
    *reinterpret_cast<float4*>(out + (size_t)(b*T_ + t0 + tt)*1024 + (g0+gg)*4) = o;
  }
}

extern "C" void kernel_launch(void* const* d_in, const int* in_sizes, int n_in,
                              void* d_out, int out_size, void* d_ws, size_t ws_size,
                              hipStream_t stream){
  const float* x    = (const float*)d_in[0];
  const float* emb0 = (const float*)d_in[1];
  const float* emb1 = (const float*)d_in[2];
  float* out = (float*)d_out;
  unsigned char* tok  = (unsigned char*)d_ws;            // 2 MiB
  unsigned char* pred = tok + (size_t)B_*CG_*T_;         // 2 MiB
  pack_kernel<<<128, 256, 0, stream>>>(x, tok);
  rosa_dp_kernel<<<(B_*CG_)/4, 256, 0, stream>>>(tok, pred);
  expand_kernel<<<512, 256, 0, stream>>>(pred, emb0, emb1, out);
}

// Round 2
// 303.575 us; speedup vs baseline: 1.1714x; 1.1714x over previous
//
#include <hip/hip_runtime.h>

#define B_ 8
#define T_ 1024
#define CG_ 256

// ---------------- pack: x (8,1024,1024) f32 -> tok rows (B*Cg, T) u8 ----------------
__global__ __launch_bounds__(256) void pack_kernel(const float* __restrict__ x,
                                                   unsigned char* __restrict__ tok){
  __shared__ unsigned char tl[256][80];          // [g][tt], 80 keeps rows 16B-aligned
  const int b  = blockIdx.x >> 4;                // 8 b * 16 t-tiles = 128 blocks
  const int t0 = (blockIdx.x & 15) << 6;
  const int g  = threadIdx.x;                    // 0..255
  const float* xb = x + ((size_t)(b*T_ + t0) * 1024) + g*4;
  for (int tt = 0; tt < 64; tt++){
    const float4 v = *reinterpret_cast<const float4*>(xb + (size_t)tt*1024);
    unsigned int t = (v.x>0.f?1u:0u) | (v.y>0.f?2u:0u) | (v.z>0.f?4u:0u) | (v.w>0.f?8u:0u);
    tl[g][tt] = (unsigned char)t;
  }
  __syncthreads();
  const int gg  = threadIdx.x >> 2;
  const int off = (threadIdx.x & 3) * 16;
  for (int it = 0; it < 4; it++){
    const int g2 = gg + it*64;
    const uint4 w = *reinterpret_cast<const uint4*>(&tl[g2][off]);
    *reinterpret_cast<uint4*>(tok + (size_t)(b*CG_ + g2)*T_ + t0 + off) = w;
  }
}

// ---------------- ROSA DP: one wave per row, all-VALU inner loop ----------------
// max across 64 lanes, valid result in lane 63 (returned to all lanes via readlane)
__device__ __forceinline__ unsigned int wave_allmax63(unsigned int v){
  int x = (int)v, t;
  t = __builtin_amdgcn_update_dpp(x, x, 0x111, 0xf, 0xf, false); x = t > x ? t : x; // row_shr:1
  t = __builtin_amdgcn_update_dpp(x, x, 0x112, 0xf, 0xf, false); x = t > x ? t : x; // row_shr:2
  t = __builtin_amdgcn_update_dpp(x, x, 0x114, 0xf, 0xf, false); x = t > x ? t : x; // row_shr:4
  t = __builtin_amdgcn_update_dpp(x, x, 0x118, 0xf, 0xf, false); x = t > x ? t : x; // row_shr:8
  t = __builtin_amdgcn_update_dpp(x, x, 0x142, 0xf, 0xf, false); x = t > x ? t : x; // row_bcast:15
  t = __builtin_amdgcn_update_dpp(x, x, 0x143, 0xf, 0xf, false); x = t > x ? t : x; // row_bcast:31
  return (unsigned int)__builtin_amdgcn_readlane(x, 63);
}

// K[j] = (run[j] << 10) | j   (run==0 entries hold K=j < 1024).
// Recurrence: K_new[j] = eq(x_j, x_i) ? K_old[j-1] + 1025 : j
//   since (run+1)<<10 | j == (run<<10 | (j-1)) + 1024 + 1. K[-1] := -1 so +1025 -> 1024.
__global__ __launch_bounds__(256, 2) void rosa_dp_kernel(const unsigned char* __restrict__ tok,
                                                         unsigned char* __restrict__ pred){
  __shared__ unsigned char tlds[4][1024];
  const int wave = threadIdx.x >> 6;
  const unsigned int lane = threadIdx.x & 63u;
  const int row = blockIdx.x * 4 + wave;
  unsigned char* mylds = &tlds[wave][0];
  {
    const uint4 v = *reinterpret_cast<const uint4*>(tok + (size_t)row*T_ + lane*16);
    *reinterpret_cast<uint4*>(mylds + lane*16) = v;
  }
  __syncthreads();

  unsigned int tokr[16], K[16], jv[16];
  #pragma unroll
  for (int k=0;k<16;k++){ tokr[k] = mylds[k*64 + lane]; jv[k] = (unsigned int)(k*64) + lane; K[k] = jv[k]; }
  const bool lane0 = (lane == 0u);

  #pragma unroll
  for (int i0 = 0; i0 < 16; i0++){
    unsigned int abr = 0u;                       // lane l collects argmax key of step i0*64+l
    #pragma unroll 1
    for (int di = 0; di < 64; di++){
      const unsigned int xi = (unsigned int)__builtin_amdgcn_readlane((int)tokr[i0], di);
      unsigned int best = 0u, carry = 0xFFFFFFFFu;
      #pragma unroll
      for (int k = 0; k <= i0; k++){
        const int rot = __builtin_amdgcn_update_dpp((int)K[k], (int)K[k], 0x13C, 0xf, 0xf, false); // wave_ror:1
        const unsigned int shifted = lane0 ? carry : (unsigned int)rot;
        carry = (unsigned int)rot;               // lane0's rot == old K[k][63] -> carry for chunk k+1
        const unsigned int t = shifted + 1025u;
        const unsigned int Kn = (tokr[k] == xi) ? t : jv[k];
        K[k] = Kn;
        const unsigned int cand = (k == i0) ? ((lane < (unsigned int)di) ? Kn : 0u) : Kn; // j<i mask
        best = cand > best ? cand : best;
      }
      const unsigned int mx = wave_allmax63(best);
      abr = (lane == (unsigned int)di) ? mx : abr;
    }
    // epilogue for this 64-step block: pred lookup + validity, lane-parallel
    unsigned int pidx = (abr & 1023u) + 1u;
    pidx = pidx > 1023u ? 1023u : pidx;          // min(best_j+1, T-1)
    const unsigned int ptok = (unsigned int)mylds[pidx];
    const unsigned int pr = (abr >= 1024u) ? ptok : 0u;  // max run==0 -> no match -> 0
    pred[(size_t)row*T_ + i0*64 + lane] = (unsigned char)pr;
  }
}

// ---------------- expand: pred (B*Cg, T) u8 -> out (B,T,C) f32 ----------------
__global__ __launch_bounds__(256) void expand_kernel(const unsigned char* __restrict__ pred,
                                                     const float* __restrict__ emb0,
                                                     const float* __restrict__ emb1,
                                                     float* __restrict__ out){
  __shared__ unsigned char pl[64][80];
  const int bid = blockIdx.x;                 // 8 b * 16 t-tiles * 4 g-tiles = 512
  const int g0 = (bid & 3) << 6;
  const int t0 = ((bid >> 2) & 15) << 6;
  const int b  = bid >> 6;
  const int k  = threadIdx.x;
  {
    const int gg = k >> 2, off = (k & 3) * 16;
    const uint4 v = *reinterpret_cast<const uint4*>(pred + (size_t)(b*CG_ + g0 + gg)*T_ + t0 + off);
    *reinterpret_cast<uint4*>(&pl[gg][off]) = v;
  }
  __syncthreads();
  const int gg = k & 63;
  const int w  = k >> 6;
  const float4 e0 = *reinterpret_cast<const float4*>(emb0 + (g0+gg)*4);
  const float4 e1 = *reinterpret_cast<const float4*>(emb1 + (g0+gg)*4);
  for (int it = 0; it < 16; it++){
    const int tt = it*4 + w;
    const unsigned int pb = pl[gg][tt];
    float4 o;
    o.x = (pb & 1u) ? e1.x : e0.x;
    o.y = (pb & 2u) ? e1.y : e0.y;
    o.z = (pb & 4u) ? e1.z : e0.z;
    o.w = (pb & 8u) ? e1.w : e0.w;
    *reinterpret_cast<float4*>(out + (size_t)(b*T_ + t0 + tt)*1024 + (g0+gg)*4) = o;
  }
}

extern "C" void kernel_launch(void* const* d_in, const int* in_sizes, int n_in,
                              void* d_out, int out_size, void* d_ws, size_t ws_size,
                              hipStream_t stream){
  const float* x    = (const float*)d_in[0];
  const float* emb0 = (const float*)d_in[1];
  const float* emb1 = (const float*)d_in[2];
  float* out = (float*)d_out;
  unsigned char* tok  = (unsigned char*)d_ws;            // 2 MiB
  unsigned char* pred = tok + (size_t)B_*CG_*T_;         // 2 MiB
  pack_kernel<<<128, 256, 0, stream>>>(x, tok);
  rosa_dp_kernel<<<(B_*CG_)/4, 256, 0, stream>>>(tok, pred);
  expand_kernel<<<512, 256, 0, stream>>>(pred, emb0, emb1, out);
}

// Round 3
// 281.170 us; speedup vs baseline: 1.2648x; 1.0797x over previous
//
#include <hip/hip_runtime.h>

#define B_ 8
#define T_ 1024
#define CG_ 256

// ---------------- pack: x (8,1024,1024) f32 -> tok rows (B*Cg, T) u8 ----------------
__global__ __launch_bounds__(256) void pack_kernel(const float* __restrict__ x,
                                                   unsigned char* __restrict__ tok){
  __shared__ unsigned char tl[256][80];          // [g][tt], 80 keeps rows 16B-aligned
  const int b  = blockIdx.x >> 4;                // 8 b * 16 t-tiles = 128 blocks
  const int t0 = (blockIdx.x & 15) << 6;
  const int g  = threadIdx.x;                    // 0..255
  const float* xb = x + ((size_t)(b*T_ + t0) * 1024) + g*4;
  for (int tt = 0; tt < 64; tt++){
    const float4 v = *reinterpret_cast<const float4*>(xb + (size_t)tt*1024);
    unsigned int t = (v.x>0.f?1u:0u) | (v.y>0.f?2u:0u) | (v.z>0.f?4u:0u) | (v.w>0.f?8u:0u);
    tl[g][tt] = (unsigned char)t;
  }
  __syncthreads();
  const int gg  = threadIdx.x >> 2;
  const int off = (threadIdx.x & 3) * 16;
  for (int it = 0; it < 4; it++){
    const int g2 = gg + it*64;
    const uint4 w = *reinterpret_cast<const uint4*>(&tl[g2][off]);
    *reinterpret_cast<uint4*>(tok + (size_t)(b*CG_ + g2)*T_ + t0 + off) = w;
  }
}

// 64-lane max reduce; result valid in lane 63, broadcast via readlane.
// mov_dpp old=undef is safe: row_mask/bank_mask full -> every lane written;
// invalid-source lanes get 0 (bound_ctrl=1), identity for unsigned max.
__device__ __forceinline__ unsigned int wave_allmax63(unsigned int v){
  int x = (int)v, t;
  t = __builtin_amdgcn_mov_dpp(x, 0x111, 0xf, 0xf, true); x = ((unsigned)t > (unsigned)x) ? t : x; // row_shr:1
  t = __builtin_amdgcn_mov_dpp(x, 0x112, 0xf, 0xf, true); x = ((unsigned)t > (unsigned)x) ? t : x; // row_shr:2
  t = __builtin_amdgcn_mov_dpp(x, 0x114, 0xf, 0xf, true); x = ((unsigned)t > (unsigned)x) ? t : x; // row_shr:4
  t = __builtin_amdgcn_mov_dpp(x, 0x118, 0xf, 0xf, true); x = ((unsigned)t > (unsigned)x) ? t : x; // row_shr:8
  t = __builtin_amdgcn_mov_dpp(x, 0x142, 0xf, 0xf, true); x = ((unsigned)t > (unsigned)x) ? t : x; // row_bcast:15
  t = __builtin_amdgcn_mov_dpp(x, 0x143, 0xf, 0xf, true); x = ((unsigned)t > (unsigned)x) ? t : x; // row_bcast:31
  return (unsigned int)__builtin_amdgcn_readlane(x, 63);
}

// Sparse ROSA DP. Per step i, candidates = {j : x[j]==x[i]} (precomputed value
// lists). State: stamped LDS val[j] = (i<<16)|run. runold valid iff stamp==i-1.
// Cells j>=i are computed too (never read by masked argmax; diagonal-invariant).
struct alignas(16) RowLds {
  unsigned int   val[1028];    // 1024 cells + dummy slot 1024 (+pad for 16B align)
  unsigned char  t[1024];      // tokens
  unsigned short vl[16*128];   // value lists, capacity 128 per token value
  unsigned int   cnt[16];      // bucket sizes
};

__global__ __launch_bounds__(256, 2) void rosa_sparse_kernel(const unsigned char* __restrict__ tok,
                                                             unsigned char* __restrict__ pred){
  __shared__ RowLds S[4];
  const int wave = threadIdx.x >> 6;
  const unsigned int lane = threadIdx.x & 63u;
  const int row = blockIdx.x * 4 + wave;
  RowLds& R = S[wave];

  // stage tokens
  {
    const uint4 v = *reinterpret_cast<const uint4*>(tok + (size_t)row*T_ + lane*16);
    *reinterpret_cast<uint4*>(&R.t[lane*16]) = v;
  }
  // init val stamps to 0xFFFF (never matches any i-1), run=0
  {
    const uint4 z = make_uint4(0xFFFF0000u,0xFFFF0000u,0xFFFF0000u,0xFFFF0000u);
    uint4* p = reinterpret_cast<uint4*>(R.val);
    p[lane] = z; p[lane+64] = z; p[lane+128] = z; p[lane+192] = z;
    if (lane == 0u) R.val[1024] = 0xFFFF0000u;
  }
  if (lane < 16u) R.cnt[lane] = 0u;
  // build value lists (order within bucket irrelevant)
  #pragma unroll
  for (int k = 0; k < 16; k++){
    const unsigned int j = (unsigned)k*64u + lane;
    const unsigned int v = R.t[j];
    const unsigned int r = atomicAdd(&R.cnt[v], 1u) & 127u;
    R.vl[v*128u + r] = (unsigned short)j;
  }
  const unsigned int cntv = R.cnt[lane & 15u];

  // pipeline prologue (step 0)
  unsigned int cur_tok = R.t[0];
  int xi = __builtin_amdgcn_readfirstlane((int)cur_tok);
  unsigned int len  = (unsigned int)__builtin_amdgcn_readlane((int)cntv, xi);
  unsigned int jl   = R.vl[(unsigned)xi*128u + lane];
  unsigned int jl2  = R.vl[(unsigned)xi*128u + 64u + lane];
  unsigned int ntok = R.t[1];
  unsigned int abr = 0u;

  #pragma unroll 2
  for (int i = 0; i < T_; i++){
    // ---- gather phase: ALL reads before ANY writes (same-step RAW safety) ----
    const unsigned int a1 = (jl >= 1u) ? (jl - 1u) : 0u;
    const unsigned int g1 = R.val[a1];
    unsigned int g2 = 0u;
    const bool two = (len > 64u);
    if (two){
      const unsigned int a2 = (jl2 >= 1u) ? (jl2 - 1u) : 0u;
      g2 = R.val[a2];
    }
    // ---- compute + write phase ----
    const unsigned int stamp_prev = (unsigned int)(i - 1);
    const unsigned int ro1 = ((g1 >> 16) == stamp_prev && jl >= 1u) ? (g1 & 0xFFFFu) : 0u;
    const unsigned int rn1 = ro1 + 1u;
    const unsigned int widx1 = (lane < len) ? jl : 1024u;
    R.val[widx1] = ((unsigned int)i << 16) | rn1;
    unsigned int best = (lane < len && jl < (unsigned int)i) ? ((rn1 << 10) | jl) : 0u;
    if (two){
      const unsigned int ro2 = ((g2 >> 16) == stamp_prev && jl2 >= 1u) ? (g2 & 0xFFFFu) : 0u;
      const unsigned int rn2 = ro2 + 1u;
      const unsigned int l2 = lane + 64u;
      const unsigned int widx2 = (l2 < len) ? jl2 : 1024u;
      R.val[widx2] = ((unsigned int)i << 16) | rn2;
      const unsigned int key2 = (l2 < len && jl2 < (unsigned int)i) ? ((rn2 << 10) | jl2) : 0u;
      best = key2 > best ? key2 : best;
    }
    // ---- prefetch for step i+1 (independent of DP state) ----
    const int nx = __builtin_amdgcn_readfirstlane((int)ntok);
    const unsigned int nlen = (unsigned int)__builtin_amdgcn_readlane((int)cntv, nx);
    const unsigned int njl  = R.vl[(unsigned)nx*128u + lane];
    const unsigned int njl2 = R.vl[(unsigned)nx*128u + 64u + lane];
    const unsigned int nntok = R.t[(i + 2 < T_) ? (i + 2) : (T_ - 1)];
    // ---- argmax reduce (off the recurrence critical path) ----
    const unsigned int mx = wave_allmax63(best);
    abr = (lane == (unsigned int)(i & 63)) ? mx : abr;
    if ((i & 63) == 63){
      unsigned int pidx = (abr & 1023u) + 1u;
      pidx = pidx > 1023u ? 1023u : pidx;
      const unsigned int pt = R.t[pidx];
      const unsigned int pr = (abr >= 1024u) ? pt : 0u;   // no candidate -> 0
      pred[(size_t)row*T_ + (i - 63) + lane] = (unsigned char)pr;
      abr = 0u;
    }
    xi = nx; len = nlen; jl = njl; jl2 = njl2; ntok = nntok;
  }
}

// ---------------- expand: pred (B*Cg, T) u8 -> out (B,T,C) f32 ----------------
__global__ __launch_bounds__(256) void expand_kernel(const unsigned char* __restrict__ pred,
                                                     const float* __restrict__ emb0,
                                                     const float* __restrict__ emb1,
                                                     float* __restrict__ out){
  __shared__ unsigned char pl[64][80];
  const int bid = blockIdx.x;                 // 8 b * 16 t-tiles * 4 g-tiles = 512
  const int g0 = (bid & 3) << 6;
  const int t0 = ((bid >> 2) & 15) << 6;
  const int b  = bid >> 6;
  const int k  = threadIdx.x;
  {
    const int gg = k >> 2, off = (k & 3) * 16;
    const uint4 v = *reinterpret_cast<const uint4*>(pred + (size_t)(b*CG_ + g0 + gg)*T_ + t0 + off);
    *reinterpret_cast<uint4*>(&pl[gg][off]) = v;
  }
  __syncthreads();
  const int gg = k & 63;
  const int w  = k >> 6;
  const float4 e0 = *reinterpret_cast<const float4*>(emb0 + (g0+gg)*4);
  const float4 e1 = *reinterpret_cast<const float4*>(emb1 + (g0+gg)*4);
  for (int it = 0; it < 16; it++){
    const int tt = it*4 + w;
    const unsigned int pb = pl[gg][tt];
    float4 o;
    o.x = (pb & 1u) ? e1.x : e0.x;
    o.y = (pb & 2u) ? e1.y : e0.y;
    o.z = (pb & 4u) ? e1.z : e0.z;
    o.w = (pb & 8u) ? e1.w : e0.w;
    *reinterpret_cast<float4*>(out + (size_t)(b*T_ + t0 + tt)*1024 + (g0+gg)*4) = o;
  }
}

extern "C" void kernel_launch(void* const* d_in, const int* in_sizes, int n_in,
                              void* d_out, int out_size, void* d_ws, size_t ws_size,
                              hipStream_t stream){
  const float* x    = (const float*)d_in[0];
  const float* emb0 = (const float*)d_in[1];
  const float* emb1 = (const float*)d_in[2];
  float* out = (float*)d_out;
  unsigned char* tok  = (unsigned char*)d_ws;            // 2 MiB
  unsigned char* pred = tok + (size_t)B_*CG_*T_;         // 2 MiB
  pack_kernel<<<128, 256, 0, stream>>>(x, tok);
  rosa_sparse_kernel<<<(B_*CG_)/4, 256, 0, stream>>>(tok, pred);
  expand_kernel<<<512, 256, 0, stream>>>(pred, emb0, emb1, out);
}

// Round 5
// 220.637 us; speedup vs baseline: 1.6118x; 1.2744x over previous
//
#include <hip/hip_runtime.h>

#define B_ 8
#define T_ 1024
#define CG_ 256

// ---------------- pack: x (8,1024,1024) f32 -> tok rows (B*Cg, T) u8 ----------------
__global__ __launch_bounds__(256) void pack_kernel(const float* __restrict__ x,
                                                   unsigned char* __restrict__ tok){
  __shared__ unsigned char tl[256][80];          // [g][tt], 80 keeps rows 16B-aligned
  const int b  = blockIdx.x >> 4;                // 8 b * 16 t-tiles = 128 blocks
  const int t0 = (blockIdx.x & 15) << 6;
  const int g  = threadIdx.x;                    // 0..255
  const float* xb = x + ((size_t)(b*T_ + t0) * 1024) + g*4;
  for (int tt = 0; tt < 64; tt++){
    const float4 v = *reinterpret_cast<const float4*>(xb + (size_t)tt*1024);
    unsigned int t = (v.x>0.f?1u:0u) | (v.y>0.f?2u:0u) | (v.z>0.f?4u:0u) | (v.w>0.f?8u:0u);
    tl[g][tt] = (unsigned char)t;
  }
  __syncthreads();
  const int gg  = threadIdx.x >> 2;
  const int off = (threadIdx.x & 3) * 16;
  for (int it = 0; it < 4; it++){
    const int g2 = gg + it*64;
    const uint4 w = *reinterpret_cast<const uint4*>(&tl[g2][off]);
    *reinterpret_cast<uint4*>(tok + (size_t)(b*CG_ + g2)*T_ + t0 + off) = w;
  }
}

// 64-lane max reduce via DPP intrinsics (compiler inserts the required
// VALU->DPP wait states and fills them with independent work). Result valid
// in lane 63 only. bound_ctrl=true: invalid source lanes read 0 (max identity).
__device__ __forceinline__ unsigned int redmax63(unsigned int v){
  int x = (int)v, t;
  t = __builtin_amdgcn_mov_dpp(x, 0x111, 0xf, 0xf, true); x = ((unsigned)t > (unsigned)x) ? t : x; // row_shr:1
  t = __builtin_amdgcn_mov_dpp(x, 0x112, 0xf, 0xf, true); x = ((unsigned)t > (unsigned)x) ? t : x; // row_shr:2
  t = __builtin_amdgcn_mov_dpp(x, 0x114, 0xf, 0xf, true); x = ((unsigned)t > (unsigned)x) ? t : x; // row_shr:4
  t = __builtin_amdgcn_mov_dpp(x, 0x118, 0xf, 0xf, true); x = ((unsigned)t > (unsigned)x) ? t : x; // row_shr:8
  t = __builtin_amdgcn_mov_dpp(x, 0x142, 0xf, 0xf, true); x = ((unsigned)t > (unsigned)x) ? t : x; // row_bcast:15
  t = __builtin_amdgcn_mov_dpp(x, 0x143, 0xf, 0xf, true); x = ((unsigned)t > (unsigned)x) ? t : x; // row_bcast:31
  return (unsigned)x;
}

// Sparse ROSA DP, branchless 2-batch. State val[j] = (stamp<<16)|run in LDS.
// Freshness: d = val - ((i-1)<<16); fresh iff d<=1024 (run in [1,1024]).
// Lists padded to 128 with sentinel (jl=1025 trash-write, a1=1026 stale-read).
struct alignas(16) RowLds {
  unsigned int  val[1028];    // 0..1023 cells, 1025 trash write, 1026 sentinel read
  unsigned char t[1040];      // tokens + zero pad (reads up to t[1026])
  unsigned int  vlu[2048];    // [16][128] packed (j<<16)|a1, batches interleaved
  unsigned int  cnt[16];
  unsigned int  pk[64];       // reduced key per step of current 64-block
  unsigned int  pktrash[64];
};

__global__ __launch_bounds__(256, 2) void rosa_sparse_kernel(const unsigned char* __restrict__ tok,
                                                             unsigned char* __restrict__ pred){
  __shared__ RowLds S[4];
  const int wave = threadIdx.x >> 6;
  const unsigned int lane = threadIdx.x & 63u;
  const int row = blockIdx.x * 4 + wave;
  RowLds& R = S[wave];

  // stage tokens + zero pad
  {
    const uint4 v = *reinterpret_cast<const uint4*>(tok + (size_t)row*T_ + lane*16);
    *reinterpret_cast<uint4*>(&R.t[lane*16]) = v;
    if (lane == 0u) *reinterpret_cast<uint4*>(&R.t[1024]) = make_uint4(0,0,0,0);
  }
  // init val stamps to 0xFFFF
  {
    const uint4 z = make_uint4(0xFFFF0000u,0xFFFF0000u,0xFFFF0000u,0xFFFF0000u);
    uint4* p = reinterpret_cast<uint4*>(R.val);
    p[lane] = z; p[lane+64] = z; p[lane+128] = z; p[lane+192] = z;
    if (lane == 0u) p[256] = z;                  // slots 1024..1027
  }
  // init vlu with sentinel entries
  {
    const unsigned int se = (1025u << 16) | 1026u;
    const uint4 s4 = make_uint4(se,se,se,se);
    uint4* p = reinterpret_cast<uint4*>(R.vlu);
    #pragma unroll
    for (int m = 0; m < 8; m++) p[m*64 + lane] = s4;
  }
  if (lane < 16u) R.cnt[lane] = 0u;
  // build value lists: entry = (j<<16) | (j==0 ? 1026 : j-1), batches interleaved
  #pragma unroll
  for (int k = 0; k < 16; k++){
    const unsigned int j = (unsigned)k*64u + lane;
    const unsigned int v = R.t[j];
    const unsigned int r = atomicAdd(&R.cnt[v], 1u) & 127u;
    const unsigned int slot = (r < 64u) ? (2u*r) : (2u*r - 127u);
    const unsigned int a1 = (j == 0u) ? 1026u : (j - 1u);
    R.vlu[(v << 7) + slot] = (j << 16) | a1;
  }

  // pipeline prologue
  const unsigned int x0 = R.t[0];
  unsigned int xn  = R.t[1];
  unsigned int xn2 = R.t[2];
  uint2 e = *reinterpret_cast<const uint2*>(&R.vlu[(x0 << 7) + (lane << 1)]);
  unsigned int eLo = e.x, eHi = e.y;

  #pragma unroll 2
  for (int i = 0; i < T_; i++){
    const unsigned int a1_1 = eLo & 0xFFFFu, jl1 = eLo >> 16;
    const unsigned int a1_2 = eHi & 0xFFFFu, jl2 = eHi >> 16;
    // gathers (all reads before any write: in-list adjacency makes RAW possible)
    const unsigned int g1 = R.val[a1_1];
    const unsigned int g2 = R.val[a1_2];
    // prefetch next step's list entries + token i+3
    const uint2 en = *reinterpret_cast<const uint2*>(&R.vlu[(xn << 7) + (lane << 1)]);
    const unsigned int xn3 = R.t[i + 3];         // padded, safe to t[1026]
    // stamp check + run update (3 ops per batch)
    const unsigned int sp = (unsigned int)(i - 1) << 16;
    const unsigned int d1 = g1 - sp;
    const unsigned int d2 = g2 - sp;
    const unsigned int rn1 = (d1 <= 1024u) ? (d1 + 1u) : 1u;
    const unsigned int rn2 = (d2 <= 1024u) ? (d2 + 1u) : 1u;
    const unsigned int st = ((unsigned int)i << 16);
    R.val[jl1] = st | rn1;
    R.val[jl2] = st | rn2;
    // keys, masked to j<i (also kills sentinels)
    unsigned int k1 = (rn1 << 10) | jl1; k1 = (jl1 < (unsigned int)i) ? k1 : 0u;
    unsigned int k2 = (rn2 << 10) | jl2; k2 = (jl2 < (unsigned int)i) ? k2 : 0u;
    unsigned int best = k1 > k2 ? k1 : k2;
    best = redmax63(best);
    unsigned int* pka = (lane == 63u) ? &R.pk[i & 63] : &R.pktrash[lane];
    *pka = best;
    if ((i & 63) == 63){
      const unsigned int ab = R.pk[lane];
      unsigned int pidx = (ab & 1023u) + 1u;
      pidx = pidx > 1023u ? 1023u : pidx;
      const unsigned int pt = R.t[pidx];
      pred[(size_t)row*T_ + (i - 63) + lane] = (unsigned char)((ab >= 1024u) ? pt : 0u);
    }
    eLo = en.x; eHi = en.y; xn = xn2; xn2 = xn3;
  }
}

// ---------------- expand: pred (B*Cg, T) u8 -> out (B,T,C) f32 ----------------
__global__ __launch_bounds__(256) void expand_kernel(const unsigned char* __restrict__ pred,
                                                     const float* __restrict__ emb0,
                                                     const float* __restrict__ emb1,
                                                     float* __restrict__ out){
  __shared__ unsigned char pl[64][80];
  const int bid = blockIdx.x;                 // 8 b * 16 t-tiles * 4 g-tiles = 512
  const int g0 = (bid & 3) << 6;
  const int t0 = ((bid >> 2) & 15) << 6;
  const int b  = bid >> 6;
  const int k  = threadIdx.x;
  {
    const int gg = k >> 2, off = (k & 3) * 16;
    const uint4 v = *reinterpret_cast<const uint4*>(pred + (size_t)(b*CG_ + g0 + gg)*T_ + t0 + off);
    *reinterpret_cast<uint4*>(&pl[gg][off]) = v;
  }
  __syncthreads();
  const int gg = k & 63;
  const int w  = k >> 6;
  const float4 e0 = *reinterpret_cast<const float4*>(emb0 + (g0+gg)*4);
  const float4 e1 = *reinterpret_cast<const float4*>(emb1 + (g0+gg)*4);
  for (int it = 0; it < 16; it++){
    const int tt = it*4 + w;
    const unsigned int pb = pl[gg][tt];
    float4 o;
    o.x = (pb & 1u) ? e1.x : e0.x;
    o.y = (pb & 2u) ? e1.y : e0.y;
    o.z = (pb & 4u) ? e1.z : e0.z;
    o.w = (pb & 8u) ? e1.w : e0.w;
    *reinterpret_cast<float4*>(out + (size_t)(b*T_ + t0 + tt)*1024 + (g0+gg)*4) = o;
  }
}

extern "C" void kernel_launch(void* const* d_in, const int* in_sizes, int n_in,
                              void* d_out, int out_size, void* d_ws, size_t ws_size,
                              hipStream_t stream){
  const float* x    = (const float*)d_in[0];
  const float* emb0 = (const float*)d_in[1];
  const float* emb1 = (const float*)d_in[2];
  float* out = (float*)d_out;
  unsigned char* tok  = (unsigned char*)d_ws;            // 2 MiB
  unsigned char* pred = tok + (size_t)B_*CG_*T_;         // 2 MiB
  pack_kernel<<<128, 256, 0, stream>>>(x, tok);
  rosa_sparse_kernel<<<(B_*CG_)/4, 256, 0, stream>>>(tok, pred);
  expand_kernel<<<512, 256, 0, stream>>>(pred, emb0, emb1, out);
}

// Round 6
// 208.920 us; speedup vs baseline: 1.7022x; 1.0561x over previous
//
#include <hip/hip_runtime.h>

#define B_ 8
#define T_ 1024
#define CG_ 256

// ---------------- pack: x (8,1024,1024) f32 -> tok rows (B*Cg, T) u8 ----------------
__global__ __launch_bounds__(256) void pack_kernel(const float* __restrict__ x,
                                                   unsigned char* __restrict__ tok){
  __shared__ unsigned char tl[256][80];          // [g][tt], 80 keeps rows 16B-aligned
  const int b  = blockIdx.x >> 4;                // 8 b * 16 t-tiles = 128 blocks
  const int t0 = (blockIdx.x & 15) << 6;
  const int g  = threadIdx.x;                    // 0..255
  const float* xb = x + ((size_t)(b*T_ + t0) * 1024) + g*4;
  for (int tt = 0; tt < 64; tt++){
    const float4 v = *reinterpret_cast<const float4*>(xb + (size_t)tt*1024);
    unsigned int t = (v.x>0.f?1u:0u) | (v.y>0.f?2u:0u) | (v.z>0.f?4u:0u) | (v.w>0.f?8u:0u);
    tl[g][tt] = (unsigned char)t;
  }
  __syncthreads();
  const int gg  = threadIdx.x >> 2;
  const int off = (threadIdx.x & 3) * 16;
  for (int it = 0; it < 4; it++){
    const int g2 = gg + it*64;
    const uint4 w = *reinterpret_cast<const uint4*>(&tl[g2][off]);
    *reinterpret_cast<uint4*>(tok + (size_t)(b*CG_ + g2)*T_ + t0 + off) = w;
  }
}

// Sparse ROSA DP. val[j] = (stamp<<16)|run; fresh iff d = val-((i-1)<<16) <= 1024.
// Lists padded with sentinel (jl=1025 trash-write, a1=1026 stale-read).
// Per-step argmax: 3-DPP 8-group max -> M8[step][group], transposed full reduce
// once per 64-step block (lane s reduces step s).
struct alignas(16) RowLds {
  unsigned int  val[1028];    // 4112 B
  unsigned char t[1040];      // 1040 B
  unsigned int  vlu[2048];    // 8192 B  [16][128] packed (j<<16)|a1, interleaved
  unsigned int  cnt[16];      // 64 B
  unsigned int  M8[576];      // 2304 B  [64 steps][9] (col 8 pad)
  unsigned int  trash[64];    // 256 B
};                            // 15968 B/wave, x4 = 63872 B

__global__ __launch_bounds__(256, 2) void rosa_sparse_kernel(const unsigned char* __restrict__ tok,
                                                             unsigned char* __restrict__ pred){
  __shared__ RowLds S[4];
  const int wave = threadIdx.x >> 6;
  const unsigned int lane = threadIdx.x & 63u;
  const int row = blockIdx.x * 4 + wave;
  RowLds& R = S[wave];

  // stage tokens + zero pad
  {
    const uint4 v = *reinterpret_cast<const uint4*>(tok + (size_t)row*T_ + lane*16);
    *reinterpret_cast<uint4*>(&R.t[lane*16]) = v;
    if (lane == 0u) *reinterpret_cast<uint4*>(&R.t[1024]) = make_uint4(0,0,0,0);
  }
  // init val stamps to 0xFFFF
  {
    const uint4 z = make_uint4(0xFFFF0000u,0xFFFF0000u,0xFFFF0000u,0xFFFF0000u);
    uint4* p = reinterpret_cast<uint4*>(R.val);
    p[lane] = z; p[lane+64] = z; p[lane+128] = z; p[lane+192] = z;
    if (lane == 0u) p[256] = z;                  // slots 1024..1027
  }
  // init vlu with sentinel entries
  {
    const unsigned int se = (1025u << 16) | 1026u;
    const uint4 s4 = make_uint4(se,se,se,se);
    uint4* p = reinterpret_cast<uint4*>(R.vlu);
    #pragma unroll
    for (int m = 0; m < 8; m++) p[m*64 + lane] = s4;
  }
  if (lane < 16u) R.cnt[lane] = 0u;
  // build value lists: entry = (j<<16) | (j==0 ? 1026 : j-1), batches interleaved
  #pragma unroll
  for (int k = 0; k < 16; k++){
    const unsigned int j = (unsigned)k*64u + lane;
    const unsigned int v = R.t[j];
    const unsigned int r = atomicAdd(&R.cnt[v], 1u) & 127u;
    const unsigned int slot = (r < 64u) ? (2u*r) : (2u*r - 127u);
    const unsigned int a1 = (j == 0u) ? 1026u : (j - 1u);
    R.vlu[(v << 7) + slot] = (j << 16) | a1;
  }

  // tokens -> registers (one chunk per reg; 4 lanes/word broadcast reads)
  unsigned int vtokk[16];
  #pragma unroll
  for (int k = 0; k < 16; k++) vtokk[k] = R.t[k*64 + lane];
  const unsigned int cntv = R.cnt[lane & 15u];
  const unsigned int lane2 = lane << 1;
  // per-lane M8 write slot: lanes 7 mod 8 -> M8[.][lane>>3], others -> trash
  const bool realw = ((lane & 7u) == 7u);
  unsigned int* const wbase = realw ? &R.M8[lane >> 3] : &R.trash[lane];
  const unsigned int ws = realw ? 9u : 0u;

  // prologue: prefetch step 0
  unsigned int s_x = (unsigned)__builtin_amdgcn_readlane((int)vtokk[0], 0);
  unsigned int lenC = (unsigned)__builtin_amdgcn_readlane((int)cntv, (int)s_x);
  unsigned int eLo, eHi;
  { const uint2 e0 = *reinterpret_cast<const uint2*>(&R.vlu[(s_x << 7) + lane2]);
    eLo = e0.x; eHi = e0.y; }

#define ROSA_STEP(I0, DI, NB, ND) do {                                          \
    const unsigned int a1_1 = eLo & 0xFFFFu, jl1 = eLo >> 16;                   \
    const unsigned int a1_2 = eHi & 0xFFFFu, jl2 = eHi >> 16;                   \
    const unsigned int g1 = R.val[a1_1];                                        \
    const unsigned int g2 = R.val[a1_2];                                        \
    const unsigned int s_xn = (unsigned)__builtin_amdgcn_readlane((int)vtokk[NB], (int)(ND)); \
    const unsigned int lenN = (unsigned)__builtin_amdgcn_readlane((int)cntv, (int)s_xn);      \
    const uint2 en = *reinterpret_cast<const uint2*>(&R.vlu[(s_xn << 7) + lane2]);            \
    const unsigned int i_ = (unsigned)((I0)*64 + (DI));                         \
    const unsigned int sp = (i_ - 1u) << 16;                                    \
    const unsigned int st = i_ << 16;                                           \
    const unsigned int d1 = g1 - sp;                                            \
    const unsigned int rn1 = (d1 <= 1024u) ? (d1 + 1u) : 1u;                    \
    R.val[jl1] = st | rn1;                                                      \
    unsigned int k1 = (rn1 << 10) | jl1; k1 = (jl1 < i_) ? k1 : 0u;             \
    unsigned int best = k1;                                                     \
    if (lenC > 64u){                                                            \
      const unsigned int d2 = g2 - sp;                                          \
      const unsigned int rn2 = (d2 <= 1024u) ? (d2 + 1u) : 1u;                  \
      R.val[jl2] = st | rn2;                                                    \
      unsigned int k2 = (rn2 << 10) | jl2; k2 = (jl2 < i_) ? k2 : 0u;           \
      best = k2 > best ? k2 : best;                                             \
    }                                                                           \
    { int bb = (int)best, tt;                                                   \
      tt = __builtin_amdgcn_mov_dpp(bb, 0x111, 0xf, 0xf, true); bb = ((unsigned)tt > (unsigned)bb) ? tt : bb; \
      tt = __builtin_amdgcn_mov_dpp(bb, 0x112, 0xf, 0xf, true); bb = ((unsigned)tt > (unsigned)bb) ? tt : bb; \
      tt = __builtin_amdgcn_mov_dpp(bb, 0x114, 0xf, 0xf, true); bb = ((unsigned)tt > (unsigned)bb) ? tt : bb; \
      wbase[ws * (unsigned)(DI)] = (unsigned)bb; }                              \
    eLo = en.x; eHi = en.y; lenC = lenN;                                        \
  } while(0)

  #pragma unroll
  for (int i0 = 0; i0 < 16; i0++){
    #pragma unroll 1
    for (int di = 0; di < 63; di++){
      ROSA_STEP(i0, di, i0, di + 1);
    }
    // peeled last step: prefetch next block's step 0 (clamped at the end)
    if (i0 < 15) ROSA_STEP(i0, 63, i0 + 1, 0);
    else         ROSA_STEP(15, 63, 15, 63);
    // block epilogue: lane s reduces M8[s][0..7] -> pred for step i0*64+s
    unsigned int ab = R.M8[lane*9u + 0u];
    #pragma unroll
    for (int k = 1; k < 8; k++){
      const unsigned int v = R.M8[lane*9u + (unsigned)k];
      ab = v > ab ? v : ab;
    }
    unsigned int pidx = (ab & 1023u) + 1u;
    pidx = pidx > 1023u ? 1023u : pidx;
    const unsigned int pt = R.t[pidx];
    pred[(size_t)row*T_ + i0*64 + lane] = (unsigned char)((ab >= 1024u) ? pt : 0u);
  }
#undef ROSA_STEP
}

// ---------------- expand: pred (B*Cg, T) u8 -> out (B,T,C) f32 ----------------
__global__ __launch_bounds__(256) void expand_kernel(const unsigned char* __restrict__ pred,
                                                     const float* __restrict__ emb0,
                                                     const float* __restrict__ emb1,
                                                     float* __restrict__ out){
  __shared__ unsigned char pl[64][80];
  const int bid = blockIdx.x;                 // 8 b * 16 t-tiles * 4 g-tiles = 512
  const int g0 = (bid & 3) << 6;
  const int t0 = ((bid >> 2) & 15) << 6;
  const int b  = bid >> 6;
  const int k  = threadIdx.x;
  {
    const int gg = k >> 2, off = (k & 3) * 16;
    const uint4 v = *reinterpret_cast<const uint4*>(pred + (size_t)(b*CG_ + g0 + gg)*T_ + t0 + off);
    *reinterpret_cast<uint4*>(&pl[gg][off]) = v;
  }
  __syncthreads();
  const int gg = k & 63;
  const int w  = k >> 6;
  const float4 e0 = *reinterpret_cast<const float4*>(emb0 + (g0+gg)*4);
  const float4 e1 = *reinterpret_cast<const float4*>(emb1 + (g0+gg)*4);
  for (int it = 0; it < 16; it++){
    const int tt = it*4 + w;
    const unsigned int pb = pl[gg][tt];
    float4 o;
    o.x = (pb & 1u) ? e1.x : e0.x;
    o.y = (pb & 2u) ? e1.y : e0.y;
    o.z = (pb & 4u) ? e1.z : e0.z;
    o.w = (pb & 8u) ? e1.w : e0.w;
    *reinterpret_cast<float4*>(out + (size_t)(b*T_ + t0 + tt)*1024 + (g0+gg)*4) = o;
  }
}

extern "C" void kernel_launch(void* const* d_in, const int* in_sizes, int n_in,
                              void* d_out, int out_size, void* d_ws, size_t ws_size,
                              hipStream_t stream){
  const float* x    = (const float*)d_in[0];
  const float* emb0 = (const float*)d_in[1];
  const float* emb1 = (const float*)d_in[2];
  float* out = (float*)d_out;
  unsigned char* tok  = (unsigned char*)d_ws;            // 2 MiB
  unsigned char* pred = tok + (size_t)B_*CG_*T_;         // 2 MiB
  pack_kernel<<<128, 256, 0, stream>>>(x, tok);
  rosa_sparse_kernel<<<(B_*CG_)/4, 256, 0, stream>>>(tok, pred);
  expand_kernel<<<512, 256, 0, stream>>>(pred, emb0, emb1, out);
}

// Round 8
// 187.247 us; speedup vs baseline: 1.8992x; 1.1157x over previous
//
#include <hip/hip_runtime.h>

#define B_ 8
#define T_ 1024
#define CG_ 256
#define CAP2 26

// ---------------- pack: x (8,1024,1024) f32 -> tok rows (B*Cg, T) u8 ----------------
__global__ __launch_bounds__(256) void pack_kernel(const float* __restrict__ x,
                                                   unsigned char* __restrict__ tok){
  __shared__ unsigned char tl[256][80];
  const int b  = blockIdx.x >> 4;
  const int t0 = (blockIdx.x & 15) << 6;
  const int g  = threadIdx.x;
  const float* xb = x + ((size_t)(b*T_ + t0) * 1024) + g*4;
  for (int tt = 0; tt < 64; tt++){
    const float4 v = *reinterpret_cast<const float4*>(xb + (size_t)tt*1024);
    unsigned int t = (v.x>0.f?1u:0u) | (v.y>0.f?2u:0u) | (v.z>0.f?4u:0u) | (v.w>0.f?8u:0u);
    tl[g][tt] = (unsigned char)t;
  }
  __syncthreads();
  const int gg  = threadIdx.x >> 2;
  const int off = (threadIdx.x & 3) * 16;
  for (int it = 0; it < 4; it++){
    const int g2 = gg + it*64;
    const uint4 w = *reinterpret_cast<const uint4*>(&tl[g2][off]);
    *reinterpret_cast<uint4*>(tok + (size_t)(b*CG_ + g2)*T_ + t0 + off) = w;
  }
}

// Bigram-sparse ROSA DP (exact lcs-DP; equals reference on masked j<i region).
// Per step i: candidates needing state = {j : x[j-1]==x[i-1] && x[j]==x[i]}.
//   val[j-1] fresh (stamp i-1)  -> rn = run+1 ;  stale -> rn = 2.
// run-1 argmax handled by lastpos[x[i]] kept in a register (lane v = lastpos[v]).
struct alignas(16) RowLds {
  unsigned int   val[1092];       // [0..1023] cells, [1024] stale dummy, [1025..1088] trash writes
  unsigned char  t[1040];         // tokens + pad
  unsigned short bg[256*CAP2];    // bigram buckets, sentinel 1025
  union {
    unsigned int cnt2[256];                                     // build phase only
    struct { unsigned int pk2[128]; unsigned int trash2[128]; } m; // main loop
  } u;
};                                 // 19744 B/wave, x4 = 78976 B -> 2 blocks/CU

__global__ __launch_bounds__(256, 2) void rosa_bigram_kernel(const unsigned char* __restrict__ tok,
                                                             unsigned char* __restrict__ pred){
  __shared__ RowLds S[4];
  const int wave = threadIdx.x >> 6;
  const unsigned int lane = threadIdx.x & 63u;
  const int row = blockIdx.x * 4 + wave;
  RowLds& R = S[wave];

  // stage tokens + pad
  { const uint4 v = *reinterpret_cast<const uint4*>(tok + (size_t)row*T_ + lane*16);
    *reinterpret_cast<uint4*>(&R.t[lane*16]) = v;
    if (lane == 0u) *reinterpret_cast<uint4*>(&R.t[1024]) = make_uint4(0,0,0,0); }
  // init val stamps to 0xFFFF (incl dummy + trash slots)
  { const uint4 z = make_uint4(0xFFFF0000u,0xFFFF0000u,0xFFFF0000u,0xFFFF0000u);
    uint4* p = reinterpret_cast<uint4*>(R.val);
    #pragma unroll
    for (int m = 0; m < 4; m++) p[m*64 + lane] = z;
    if (lane < 17u) p[256 + lane] = z; }                 // words 1024..1091
  // zero bigram counters (aliased with pk2/trash2 -- used only during build)
  *reinterpret_cast<uint4*>(&R.u.cnt2[lane*4]) = make_uint4(0,0,0,0);
  // fill bg with sentinel 1025
  { const unsigned int s2 = 1025u | (1025u << 16);
    const uint4 s4 = make_uint4(s2,s2,s2,s2);
    uint4* p = reinterpret_cast<uint4*>(R.bg);
    #pragma unroll
    for (int m = 0; m < 13; m++) p[m*64 + lane] = s4; }  // 13*64*16 B = 13312 B
  // build bigram lists (same-wave DS ordering guarantees t/cnt visibility)
  #pragma unroll
  for (int k = 0; k < 16; k++){
    const unsigned int j = (unsigned)k*64u + lane;
    if (j >= 1u){
      const unsigned int v2 = ((unsigned)R.t[j-1] << 4) | (unsigned)R.t[j];
      const unsigned int r = atomicAdd(&R.u.cnt2[v2], 1u);
      if (r < (unsigned)CAP2) R.bg[v2*CAP2 + r] = (unsigned short)j;
    }
  }

  // tokens -> registers
  unsigned int vtokk[16];
  #pragma unroll
  for (int k = 0; k < 16; k++) vtokk[k] = R.t[k*64 + lane];

  unsigned int lp = 0xFFFFFFFFu;          // lastpos[v] in lane v (as signed: -1 = none)
  const bool lane26 = (lane < (unsigned)CAP2);
  const bool lane0  = (lane == 0u);
  // pk pair-write routing: lane15 -> pk2[0..63], lane31 -> pk2[64..127], else trash
  unsigned int* wbase; unsigned int wmul;
  if (lane == 15u)      { wbase = &R.u.m.pk2[0];          wmul = 1u; }
  else if (lane == 31u) { wbase = &R.u.m.pk2[64];         wmul = 1u; }
  else                  { wbase = &R.u.m.trash2[2u*lane]; wmul = 0u; }
  const unsigned int trashw = 1025u + lane;

  int s_xi  = __builtin_amdgcn_readlane((int)vtokk[0], 0);
  int s_xp1 = __builtin_amdgcn_readlane((int)vtokk[0], 1);
  unsigned int jl = 1025u;                // step-0 entries: sentinel (step 0 has no candidates)
  int i = 0;

#define RSTEP(RES, NEXTTOK_EXPR) do {                                              \
    const int s_x2n = (s_xi << 4) | s_xp1;                                         \
    unsigned int en = (unsigned int)R.bg[(unsigned)s_x2n * CAP2 + lane];           \
    const unsigned int a1 = jl - 1u;                                               \
    const unsigned int g  = R.val[a1];                                             \
    const int s_xp2 = (NEXTTOK_EXPR);                                              \
    const int s_lp = __builtin_amdgcn_readlane((int)lp, s_xi);                     \
    const unsigned int s_keya = (s_lp < 0) ? 0u : (1024u + (unsigned)s_lp);        \
    lp = (lane == (unsigned)s_xi) ? (unsigned)i : lp;                              \
    const unsigned int d = g - ((unsigned)(i - 1) << 16);                          \
    const unsigned int rn = (d <= 1024u) ? (d + 1u) : 2u;                          \
    const unsigned int widx = (jl <= 1023u) ? jl : trashw;                         \
    R.val[widx] = ((unsigned)i << 16) | rn;                                        \
    unsigned int key = (rn << 10) | jl;                                            \
    key = (jl < (unsigned)i) ? key : 0u;                                           \
    const unsigned int keym = key > s_keya ? key : s_keya;                         \
    key = lane0 ? keym : key;                                                      \
    { int bb = (int)key, tt;                                                       \
      tt = __builtin_amdgcn_mov_dpp(bb, 0x111, 0xf, 0xf, true); bb = ((unsigned)tt > (unsigned)bb) ? tt : bb; \
      tt = __builtin_amdgcn_mov_dpp(bb, 0x112, 0xf, 0xf, true); bb = ((unsigned)tt > (unsigned)bb) ? tt : bb; \
      tt = __builtin_amdgcn_mov_dpp(bb, 0x114, 0xf, 0xf, true); bb = ((unsigned)tt > (unsigned)bb) ? tt : bb; \
      tt = __builtin_amdgcn_mov_dpp(bb, 0x118, 0xf, 0xf, true); bb = ((unsigned)tt > (unsigned)bb) ? tt : bb; \
      RES = (unsigned)bb; }                                                        \
    jl = lane26 ? en : 1025u;                                                      \
    s_xi = s_xp1; s_xp1 = s_xp2; i++;                                              \
  } while(0)

  #pragma unroll
  for (int i0 = 0; i0 < 16; i0++){
    unsigned int resA, resB;
    #pragma unroll 1
    for (int dp = 0; dp < 31; dp++){
      const int di = dp * 2;
      RSTEP(resA, __builtin_amdgcn_readlane((int)vtokk[i0], di + 2));
      RSTEP(resB, __builtin_amdgcn_readlane((int)vtokk[i0], di + 3));
      *reinterpret_cast<uint2*>(wbase + wmul * (unsigned)di) = make_uint2(resA, resB);
    }
    { // peel pair (62,63): x[i+2] comes from next chunk (clamped at the very end)
      const int nc = (i0 < 15) ? (i0 + 1) : 15;
      RSTEP(resA, __builtin_amdgcn_readlane((int)vtokk[nc], (i0 < 15) ? 0 : 62));
      RSTEP(resB, __builtin_amdgcn_readlane((int)vtokk[nc], (i0 < 15) ? 1 : 63));
      *reinterpret_cast<uint2*>(wbase + wmul * 62u) = make_uint2(resA, resB);
    }
    // epilogue: lane s finalizes step i0*64+s
    const unsigned int ab0 = R.u.m.pk2[lane];
    const unsigned int ab1 = R.u.m.pk2[64u + lane];
    const unsigned int ab = ab0 > ab1 ? ab0 : ab1;
    unsigned int pidx = (ab & 1023u) + 1u;
    pidx = pidx > 1023u ? 1023u : pidx;
    const unsigned int pt = R.t[pidx];
    pred[(size_t)row*T_ + i0*64 + lane] = (unsigned char)((ab >= 1024u) ? pt : 0u);
  }
#undef RSTEP
}

// ---------------- expand: pred (B*Cg, T) u8 -> out (B,T,C) f32 ----------------
__global__ __launch_bounds__(256) void expand_kernel(const unsigned char* __restrict__ pred,
                                                     const float* __restrict__ emb0,
                                                     const float* __restrict__ emb1,
                                                     float* __restrict__ out){
  __shared__ unsigned char pl[64][80];
  const int bid = blockIdx.x;
  const int g0 = (bid & 3) << 6;
  const int t0 = ((bid >> 2) & 15) << 6;
  const int b  = bid >> 6;
  const int k  = threadIdx.x;
  {
    const int gg = k >> 2, off = (k & 3) * 16;
    const uint4 v = *reinterpret_cast<const uint4*>(pred + (size_t)(b*CG_ + g0 + gg)*T_ + t0 + off);
    *reinterpret_cast<uint4*>(&pl[gg][off]) = v;
  }
  __syncthreads();
  const int gg = k & 63;
  const int w  = k >> 6;
  const float4 e0 = *reinterpret_cast<const float4*>(emb0 + (g0+gg)*4);
  const float4 e1 = *reinterpret_cast<const float4*>(emb1 + (g0+gg)*4);
  for (int it = 0; it < 16; it++){
    const int tt = it*4 + w;
    const unsigned int pb = pl[gg][tt];
    float4 o;
    o.x = (pb & 1u) ? e1.x : e0.x;
    o.y = (pb & 2u) ? e1.y : e0.y;
    o.z = (pb & 4u) ? e1.z : e0.z;
    o.w = (pb & 8u) ? e1.w : e0.w;
    *reinterpret_cast<float4*>(out + (size_t)(b*T_ + t0 + tt)*1024 + (g0+gg)*4) = o;
  }
}

extern "C" void kernel_launch(void* const* d_in, const int* in_sizes, int n_in,
                              void* d_out, int out_size, void* d_ws, size_t ws_size,
                              hipStream_t stream){
  const float* x    = (const float*)d_in[0];
  const float* emb0 = (const float*)d_in[1];
  const float* emb1 = (const float*)d_in[2];
  float* out = (float*)d_out;
  unsigned char* tok  = (unsigned char*)d_ws;
  unsigned char* pred = tok + (size_t)B_*CG_*T_;
  pack_kernel<<<128, 256, 0, stream>>>(x, tok);
  rosa_bigram_kernel<<<(B_*CG_)/4, 256, 0, stream>>>(tok, pred);
  expand_kernel<<<512, 256, 0, stream>>>(pred, emb0, emb1, out);
}